// Round 2
// baseline (254.238 us; speedup 1.0000x reference)
//
#include <hip/hip_runtime.h>
#include <math.h>

#define D 2048
#define NT 512            // 8 waves per block, one ROW per wave
#define ROWS_PER_BLOCK 8
#define V_PER_LANE 8      // 64 lanes * 8 float4 = 512 float4 = 2048 floats = D
#define V4 (D / 4)        // 512 float4 per row == NT threads

typedef float floatx4 __attribute__((ext_vector_type(4)));

__global__ __launch_bounds__(NT) void fused_gate_kernel(
    const float* __restrict__ x,
    const float* __restrict__ ema_mean,
    const float* __restrict__ ema_sq,
    const float* __restrict__ ema_out,
    const float* __restrict__ surp_ema,
    const float* __restrict__ log_tau,
    const float* __restrict__ log_sigma,
    const float* __restrict__ log_w_raw,
    float* __restrict__ out) {
  // per-column constants, shared by every row in the block
  __shared__ floatx4 s_inv[V4];   // 8 KB  1/sqrt(max(ema_sq-mu^2,1e-4))
  __shared__ floatx4 s_mui[V4];   // 8 KB  mu * inv
  __shared__ floatx4 s_e[V4];     // 8 KB  ema_out

  const int t = threadIdx.x;
  const int lane = t & 63;
  const int wave = t >> 6;
  const int row = blockIdx.x * ROWS_PER_BLOCK + wave;

  const float* __restrict__ xr = x + (size_t)row * D;
  float* __restrict__ outr = out + (size_t)row * D;

  // --- 1) issue the 3 ema loads FIRST (oldest in the vmcnt queue) ---
  const floatx4 mv  = ((const floatx4*)ema_mean)[t];
  const floatx4 qv  = ((const floatx4*)ema_sq)[t];
  const floatx4 ev0 = ((const floatx4*)ema_out)[t];

  // --- 2) issue ALL 8 x loads back-to-back; they stay outstanding
  //        across the LDS fill + barrier (vmcnt(8) drains only ema) ---
  floatx4 xv[V_PER_LANE];
#pragma unroll
  for (int i = 0; i < V_PER_LANE; ++i)
    xv[i] = ((const floatx4*)xr)[lane + i * 64];

  // scalar transforms (uniform; SMEM path, lgkmcnt)
  const float tau    = __expf(log_tau[0]);
  const float sigma  = log1pf(__expf(log_sigma[0]));   // softplus
  const float w      = log1pf(__expf(log_w_raw[0]));   // softplus
  const float surp_e = surp_ema[0];

  // --- 3) LDS fill from the ema loads (one float4 column per thread) ---
  {
    floatx4 iv, miv;
#pragma unroll
    for (int j = 0; j < 4; ++j) {
      const float mu  = mv[j];
      const float var = fmaxf(fmaf(-mu, mu, qv[j]), 1e-4f);
      iv[j]  = __builtin_amdgcn_rsqf(var);   // ~= 1/(std+1e-5)
      miv[j] = mu * iv[j];
    }
    s_inv[t] = iv;
    s_mui[t] = miv;
    s_e[t]   = ev0;
  }
  __syncthreads();

  // gelu-tanh via sigmoid: g = x * rcp(1 + exp(x*(c1 + c2*x^2)))
  const float c1 = -2.0f * 0.7978845608028654f;        // -2*sqrt(2/pi)
  const float c2 = c1 * 0.044715f;

  float s_absz = 0.f, s_o2 = 0.f, s_dot = 0.f, s_e2 = 0.f;

  // --- 4) reduction pass: consume xv[i] in issue order (vmcnt 7..0),
  //        column constants from LDS (lgkm pipe, no vm pollution) ---
#pragma unroll
  for (int i = 0; i < V_PER_LANE; ++i) {
    const int v = lane + i * 64;
    const floatx4 iv  = s_inv[v];
    const floatx4 miv = s_mui[v];
    const floatx4 ev  = s_e[v];
#pragma unroll
    for (int j = 0; j < 4; ++j) {
      const float xx = xv[i][j];
      const float x2 = xx * xx;
      const float u2 = xx * fmaf(c2, x2, c1);           // -2*inner
      const float g  = xx * __builtin_amdgcn_rcpf(1.0f + __expf(u2));
      s_absz += fabsf(fmaf(xx, iv[j], -miv[j]));        // |(x-mu)/std|
      const float e = ev[j];
      s_o2  = fmaf(g, g, s_o2);
      s_dot = fmaf(g, e, s_dot);
      s_e2  = fmaf(e, e, s_e2);
    }
  }

  // in-wave butterfly reduction: every lane ends with the row totals
#pragma unroll
  for (int off = 32; off > 0; off >>= 1) {
    s_absz += __shfl_xor(s_absz, off);
    s_o2   += __shfl_xor(s_o2, off);
    s_dot  += __shfl_xor(s_dot, off);
    s_e2   += __shfl_xor(s_e2, off);
  }

  const float mean_absz = s_absz * (1.0f / (float)D);
  const float surp_raw  = tanhf(sigma * mean_absz);     // once per row
  const float surp_mod  = fmaxf(surp_raw - surp_e, 0.0f);
  const float inv_no = __builtin_amdgcn_rsqf(fmaxf(s_o2, 1e-24f));
  const float inv_ne = __builtin_amdgcn_rsqf(fmaxf(s_e2, 1e-24f));
  float cs = s_dot * inv_no * inv_ne;
  cs = fminf(fmaxf(cs, -1.0f), 1.0f);
  const float gate = __expf(-tau * cs) * (1.0f + w * surp_mod);

  // --- 5) store pass: RECOMPUTE gelu from the registered xv (frees the
  //        o[32] array -> VGPRs go to the 8-deep load pipeline instead) ---
#pragma unroll
  for (int i = 0; i < V_PER_LANE; ++i) {
    const int v = lane + i * 64;
    floatx4 r;
#pragma unroll
    for (int j = 0; j < 4; ++j) {
      const float xx = xv[i][j];
      const float x2 = xx * xx;
      const float u2 = xx * fmaf(c2, x2, c1);
      const float g  = xx * __builtin_amdgcn_rcpf(1.0f + __expf(u2));
      r[j] = g * gate;
    }
    __builtin_nontemporal_store(r, (floatx4*)outr + v);  // keep out of L3
  }
}

extern "C" void kernel_launch(void* const* d_in, const int* in_sizes, int n_in,
                              void* d_out, int out_size, void* d_ws, size_t ws_size,
                              hipStream_t stream) {
  const float* x        = (const float*)d_in[0];
  const float* ema_mean = (const float*)d_in[1];
  const float* ema_sq   = (const float*)d_in[2];
  const float* ema_out  = (const float*)d_in[3];
  const float* surp_ema = (const float*)d_in[4];
  const float* log_tau  = (const float*)d_in[5];
  const float* log_sig  = (const float*)d_in[6];
  const float* log_wr   = (const float*)d_in[7];
  float* out = (float*)d_out;

  const int rows = in_sizes[0] / D;  // B*T = 16384
  fused_gate_kernel<<<rows / ROWS_PER_BLOCK, NT, 0, stream>>>(
      x, ema_mean, ema_sq, ema_out, surp_ema, log_tau, log_sig, log_wr, out);
}

// Round 3
// 242.634 us; speedup vs baseline: 1.0478x; 1.0478x over previous
//
#include <hip/hip_runtime.h>
#include <math.h>

#define D 2048
#define NT 256            // 4 waves per block, one ROW per wave
#define ROWS_PER_BLOCK 4
#define V_PER_LANE 8      // 64 lanes * 8 float4 = 512 float4 = 2048 floats = D

typedef float floatx4 __attribute__((ext_vector_type(4)));

__global__ __launch_bounds__(NT) void fused_gate_kernel(
    const float* __restrict__ x,
    const float* __restrict__ ema_mean,
    const float* __restrict__ ema_sq,
    const float* __restrict__ ema_out,
    const float* __restrict__ surp_ema,
    const float* __restrict__ log_tau,
    const float* __restrict__ log_sigma,
    const float* __restrict__ log_w_raw,
    float* __restrict__ out) {
  const int t = threadIdx.x;
  const int lane = t & 63;
  const int wave = t >> 6;
  const int row = blockIdx.x * ROWS_PER_BLOCK + wave;

  const float* __restrict__ xr = x + (size_t)row * D;
  float* __restrict__ outr = out + (size_t)row * D;

  // scalar transforms (uniform; scalar-unit loads)
  const float tau    = __expf(log_tau[0]);
  const float sigma  = log1pf(__expf(log_sigma[0]));   // softplus
  const float w      = log1pf(__expf(log_w_raw[0]));   // softplus
  const float surp_e = surp_ema[0];

  // gelu-tanh via sigmoid: g = x * rcp(1 + exp(x*(c1 + c2*x^2)))
  const float c1 = -2.0f * 0.7978845608028654f;        // -2*sqrt(2/pi)
  const float c2 = c1 * 0.044715f;

  float o[V_PER_LANE * 4];
  float s_absz = 0.f, s_o2 = 0.f, s_dot = 0.f, s_e2 = 0.f;

#pragma unroll
  for (int i = 0; i < V_PER_LANE; ++i) {
    const int v = lane + i * 64;  // float4 index within the row
    const floatx4 xv = __builtin_nontemporal_load((const floatx4*)xr + v);
    const floatx4 mv = ((const floatx4*)ema_mean)[v];
    const floatx4 qv = ((const floatx4*)ema_sq)[v];
    const floatx4 ev = ((const floatx4*)ema_out)[v];
#pragma unroll
    for (int j = 0; j < 4; ++j) {
      const float xx = xv[j];
      const float x2 = xx * xx;
      const float u2 = xx * fmaf(c2, x2, c1);           // -2*inner
      const float g  = xx * __builtin_amdgcn_rcpf(1.0f + __expf(u2));
      o[i * 4 + j] = g;
      const float mu  = mv[j];
      const float var = fmaxf(fmaf(-mu, mu, qv[j]), 1e-4f);
      const float inv = __builtin_amdgcn_rsqf(var);     // ~= 1/(std+1e-5)
      s_absz += fabsf((xx - mu) * inv);
      const float e = ev[j];
      s_o2  = fmaf(g, g, s_o2);
      s_dot = fmaf(g, e, s_dot);
      s_e2  = fmaf(e, e, s_e2);
    }
  }

  // in-wave butterfly reduction: every lane ends with the row totals
#pragma unroll
  for (int off = 32; off > 0; off >>= 1) {
    s_absz += __shfl_xor(s_absz, off);
    s_o2   += __shfl_xor(s_o2, off);
    s_dot  += __shfl_xor(s_dot, off);
    s_e2   += __shfl_xor(s_e2, off);
  }

  const float mean_absz = s_absz * (1.0f / (float)D);
  const float surp_raw  = tanhf(sigma * mean_absz);     // once per row
  const float surp_mod  = fmaxf(surp_raw - surp_e, 0.0f);
  const float inv_no = __builtin_amdgcn_rsqf(fmaxf(s_o2, 1e-24f));
  const float inv_ne = __builtin_amdgcn_rsqf(fmaxf(s_e2, 1e-24f));
  float cs = s_dot * inv_no * inv_ne;
  cs = fminf(fmaxf(cs, -1.0f), 1.0f);
  const float gate = __expf(-tau * cs) * (1.0f + w * surp_mod);

  // PLAIN stores (single-variable change vs R0): let L2/MALL absorb the
  // write stream like fillBufferAligned's 6.8 TB/s path does.
#pragma unroll
  for (int i = 0; i < V_PER_LANE; ++i) {
    const int v = lane + i * 64;
    floatx4 r;
    r[0] = o[i * 4 + 0] * gate;
    r[1] = o[i * 4 + 1] * gate;
    r[2] = o[i * 4 + 2] * gate;
    r[3] = o[i * 4 + 3] * gate;
    ((floatx4*)outr)[v] = r;
  }
}

extern "C" void kernel_launch(void* const* d_in, const int* in_sizes, int n_in,
                              void* d_out, int out_size, void* d_ws, size_t ws_size,
                              hipStream_t stream) {
  const float* x        = (const float*)d_in[0];
  const float* ema_mean = (const float*)d_in[1];
  const float* ema_sq   = (const float*)d_in[2];
  const float* ema_out  = (const float*)d_in[3];
  const float* surp_ema = (const float*)d_in[4];
  const float* log_tau  = (const float*)d_in[5];
  const float* log_sig  = (const float*)d_in[6];
  const float* log_wr   = (const float*)d_in[7];
  float* out = (float*)d_out;

  const int rows = in_sizes[0] / D;  // B*T = 16384
  fused_gate_kernel<<<rows / ROWS_PER_BLOCK, NT, 0, stream>>>(
      x, ema_mean, ema_sq, ema_out, surp_ema, log_tau, log_sig, log_wr, out);
}